// Round 7
// baseline (522.120 us; speedup 1.0000x reference)
//
#include <hip/hip_runtime.h>
#include <cstddef>

#define HW 16384
#define WID 128

typedef __attribute__((ext_vector_type(8))) short short8;
typedef __attribute__((ext_vector_type(4))) float f32x4;

__device__ __forceinline__ int wstart(int i) {
    // K=7, DIL=2, L=128: nh*d = 6
    if (i < 6) return i & 1;
    if (i >= 122) return 114 + (i & 1);
    return i - 6;
}
__device__ __forceinline__ int pbstart(int i) {
    if (i < 6) return 6 - (i >> 1);
    if (i >= 122) return (127 - i) >> 1;
    return 3;
}

__device__ __forceinline__ unsigned short bf16rne(float f) {
    unsigned u = __builtin_bit_cast(unsigned, f);
    u += 0x7FFFu + ((u >> 16) & 1u);
    return (unsigned short)(u >> 16);
}
__device__ __forceinline__ void bsplit(float f, unsigned short& h, unsigned short& l) {
    h = bf16rne(f);
    float hf = __builtin_bit_cast(float, ((unsigned)h) << 16);
    l = bf16rne(f - hf);
}

// ---------------- transpose + bf16 hi/lo split: [C][HW] fp32 -> [C/32][HW][32] ----------------
__global__ __launch_bounds__(256) void pack_t(const float* __restrict__ src, size_t bstr,
                                              unsigned short* __restrict__ dh,
                                              unsigned short* __restrict__ dl) {
    __shared__ float sm[32][260];
    const int p0 = blockIdx.x * 256, c32 = blockIdx.y, b = blockIdx.z;
    const float* s = src + (size_t)b * bstr + (size_t)(c32 * 32) * HW + p0;
    const int t = threadIdx.x;
    const int rr = t >> 3, f = t & 7;
#pragma unroll
    for (int u = 0; u < 8; u++) {
        float4 v = *(const float4*)(s + (size_t)rr * HW + (f + 8 * u) * 4);
        *(float4*)&sm[rr][(f + 8 * u) * 4] = v;
    }
    __syncthreads();
    size_t off = ((size_t)(b * 8 + c32) * HW + p0 + t) * 32;
#pragma unroll
    for (int w = 0; w < 4; w++) {
        short8 vh, vl;
#pragma unroll
        for (int e = 0; e < 8; e++) {
            unsigned short h, lo_;
            bsplit(sm[w * 8 + e][t], h, lo_);
            vh[e] = (short)h;
            vl[e] = (short)lo_;
        }
        *(short8*)&dh[off + w * 8] = vh;
        *(short8*)&dl[off + w * 8] = vl;
    }
}

// ---------------- split-bf16 MFMA GEMM: Y[b,m,n] = W[m,:]·X[b,:,n] + bias[m] --------
// A = W fp32 [M][256] split in-kernel. B = x packed hi/lo bf16 [b][8][HW][32].
// 128x128 tile, BK=32, 256 thr = 4 waves (2m x 2n), 4x4 16x16x32 frags per wave.
// QKV mode: M=768, m-tile pairs = {q,k,v}; RoPE fused into epilogue for q,k.
template <bool QKV>
__global__ __launch_bounds__(256, 2) void gemm_mfma(
    const float* __restrict__ Wm, const unsigned short* __restrict__ xh,
    const unsigned short* __restrict__ xl, const float* __restrict__ bias,
    const float* __restrict__ sinp, const float* __restrict__ cosp,
    float* __restrict__ Y, int NMT, int MT) {
    __shared__ unsigned short As_h[128][40], As_l[128][40];
    __shared__ unsigned short Bs_h[128][40], Bs_l[128][40];
    // XCD-aware decode: 8 XCDs, each owns 16 n-tiles; m fastest for B-panel L2 reuse.
    const int bid = blockIdx.x;
    const int xcd = bid & 7, r = bid >> 3;
    const int mt = r % NMT;
    const int q2 = r / NMT;
    const int nt = xcd * 16 + (q2 & 15);
    const int b = q2 >> 4;
    const int t = threadIdx.x;
    const int lane = t & 63, wid = t >> 6;
    const int wm = wid >> 1, wn = wid & 1;
    const int m0 = mt * 128;

    f32x4 acc[4][4];
#pragma unroll
    for (int i = 0; i < 4; i++)
#pragma unroll
        for (int j = 0; j < 4; j++) acc[i][j] = (f32x4){0.f, 0.f, 0.f, 0.f};

    const int sr = t >> 1, sh = t & 1;  // staging: row, k-half
    const float* arow = Wm + (size_t)(m0 + sr) * 256 + sh * 16;
    const unsigned short* bh_b = xh + ((size_t)(b * 8) * HW + (size_t)nt * 128 + sr) * 32 + sh * 16;
    const unsigned short* bl_b = xl + ((size_t)(b * 8) * HW + (size_t)nt * 128 + sr) * 32 + sh * 16;

    for (int ks = 0; ks < 8; ks++) {
        // stage A (fp32 -> hi/lo bf16)
        {
            const float* ap = arow + ks * 32;
#pragma unroll
            for (int g = 0; g < 2; g++) {
                float4 f0 = *(const float4*)(ap + g * 8);
                float4 f1 = *(const float4*)(ap + g * 8 + 4);
                float ff[8] = {f0.x, f0.y, f0.z, f0.w, f1.x, f1.y, f1.z, f1.w};
                short8 vh, vl;
#pragma unroll
                for (int e = 0; e < 8; e++) {
                    unsigned short h, lo_;
                    bsplit(ff[e], h, lo_);
                    vh[e] = (short)h;
                    vl[e] = (short)lo_;
                }
                *(short8*)&As_h[sr][sh * 16 + g * 8] = vh;
                *(short8*)&As_l[sr][sh * 16 + g * 8] = vl;
            }
        }
        // stage B (pre-packed bf16)
        {
            const unsigned short* bp = bh_b + (size_t)ks * HW * 32;
            const unsigned short* lp = bl_b + (size_t)ks * HW * 32;
            *(short8*)&Bs_h[sr][sh * 16] = *(const short8*)(bp);
            *(short8*)&Bs_h[sr][sh * 16 + 8] = *(const short8*)(bp + 8);
            *(short8*)&Bs_l[sr][sh * 16] = *(const short8*)(lp);
            *(short8*)&Bs_l[sr][sh * 16 + 8] = *(const short8*)(lp + 8);
        }
        __syncthreads();
        const int k8 = (lane >> 4) * 8;
        short8 a_h[4], a_l[4];
#pragma unroll
        for (int mi = 0; mi < 4; mi++) {
            int am = wm * 64 + mi * 16 + (lane & 15);
            a_h[mi] = *(const short8*)&As_h[am][k8];
            a_l[mi] = *(const short8*)&As_l[am][k8];
        }
#pragma unroll
        for (int ni = 0; ni < 4; ni++) {
            int bn = wn * 64 + ni * 16 + (lane & 15);
            short8 b_h = *(const short8*)&Bs_h[bn][k8];
            short8 b_l = *(const short8*)&Bs_l[bn][k8];
#pragma unroll
            for (int mi = 0; mi < 4; mi++) {
                acc[mi][ni] = __builtin_amdgcn_mfma_f32_16x16x32_bf16(a_h[mi], b_h, acc[mi][ni], 0, 0, 0);
                acc[mi][ni] = __builtin_amdgcn_mfma_f32_16x16x32_bf16(a_h[mi], b_l, acc[mi][ni], 0, 0, 0);
                acc[mi][ni] = __builtin_amdgcn_mfma_f32_16x16x32_bf16(a_l[mi], b_h, acc[mi][ni], 0, 0, 0);
            }
        }
        __syncthreads();
    }

    // epilogue: bias (+ RoPE + q-scale for QKV), store fp32
    const int col = lane & 15, rq = (lane >> 4) * 4;
    const int s = QKV ? (mt >> 1) : 3;
#pragma unroll
    for (int mi = 0; mi < 4; mi++) {
        int mrow = m0 + wm * 64 + mi * 16 + rq;
        float b0 = bias[mrow], b1 = bias[mrow + 1], b2 = bias[mrow + 2], b3 = bias[mrow + 3];
#pragma unroll
        for (int ni = 0; ni < 4; ni++) {
            int p = nt * 128 + wn * 64 + ni * 16 + col;
            float v0 = acc[mi][ni][0] + b0, v1 = acc[mi][ni][1] + b1;
            float v2 = acc[mi][ni][2] + b2, v3 = acc[mi][ni][3] + b3;
            if (QKV && s < 2) {
                int d0 = (mi & 1) * 16 + rq;
                const float* cp = cosp + (size_t)p * 32 + d0;
                const float* sp = sinp + (size_t)p * 32 + d0;
                float c0 = cp[0], c1 = cp[1], c2 = cp[2], c3 = cp[3];
                float s0 = sp[0], s1 = sp[1], s2 = sp[2], s3 = sp[3];
                float n0 = v0 * c0 - v1 * s0, n1 = v1 * c1 + v0 * s1;
                float n2 = v2 * c2 - v3 * s2, n3 = v3 * c3 + v2 * s3;
                if (s == 0) {
                    const float sc = 0.17677669529663687f;
                    n0 *= sc; n1 *= sc; n2 *= sc; n3 *= sc;
                }
                v0 = n0; v1 = n1; v2 = n2; v3 = n3;
            }
            float* yp = Y + ((size_t)b * MT + mrow) * HW + p;
            yp[0] = v0;
            yp[HW] = v1;
            yp[2 * HW] = v2;
            yp[3 * HW] = v3;
        }
    }
}

// ---------------- Neighborhood attention + fused LePE, v2 ----------------
// 512 threads = 4 pixel-rows x 128 cols of one (b, head). 16-row window staged
// per channel in a SINGLE 8 KB LDS buffer; next channel's plane is prefetched
// into registers during compute (async-stage split). XCD-swizzled grid so the
// 4 i-tiles sharing halo rows land on one XCD's L2. Grid: 1024 blocks flat.
__global__ __launch_bounds__(512) void attn_k(const float* __restrict__ qkv,
                                              const float* __restrict__ rpb,
                                              const float* __restrict__ wl,
                                              const float* __restrict__ bl,
                                              float* __restrict__ out) {
    __shared__ float sm[16 * 128];
    const int t = threadIdx.x;
    const int ty = t >> 7;   // 0..3
    const int j = t & 127;
    // XCD swizzle: xcd = bid&7 owns i-tiles [xcd*4, xcd*4+4) for every (n,b)
    const int bid = blockIdx.x;
    const int xcd = bid & 7, rr = bid >> 3;     // rr in [0,128)
    const int it = xcd * 4 + (rr & 3);          // i-tile 0..31
    const int nb = rr >> 2;                     // 0..31
    const int n = nb & 7, b = nb >> 3;
    const int i0 = it * 4;
    const int i = i0 + ty;
    const int r0 = wstart(i0);   // window rows r0..r0+15 cover attn+lepe for i0..i0+3

    const float* qb = qkv + ((size_t)b * 768 + n * 32) * HW;
    const float* kb = qb + (size_t)256 * HW;
    const float* vb = qb + (size_t)512 * HW;
    const int p = i * WID + j;

    const int hs = wstart(i), ws_ = wstart(j);
    const int ph = pbstart(i), pw = pbstart(j);

    // per-thread staging offsets (4 elements: rows ty+4s, col j), clamped at row 127
    int gofs[4];
#pragma unroll
    for (int s = 0; s < 4; s++) {
        int g = r0 + ty + 4 * s;
        if (g > 127) g = 127;
        gofs[s] = g * WID + j;
    }

    float sc[49];
    const float* rp = rpb + n * 169;
#pragma unroll
    for (int ki = 0; ki < 7; ki++)
#pragma unroll
        for (int kj = 0; kj < 7; kj++)
            sc[ki * 7 + kj] = rp[(ph + ki) * 13 + (pw + kj)];

    const float* smb = sm + (hs - r0) * WID + ws_;  // attn base; offsets ki*256+kj*2

    // ---- QK^T pass (prefetch c+1 into regs while computing c) ----
    float rg[4], qn;
#pragma unroll
    for (int s = 0; s < 4; s++) rg[s] = kb[gofs[s]];
    qn = qb[p];
    for (int c = 0; c < 32; c++) {
        __syncthreads();  // all readers of sm (iter c-1) done
#pragma unroll
        for (int s = 0; s < 4; s++) sm[(ty + 4 * s) * WID + j] = rg[s];
        float qc = qn;
        if (c < 31) {
            const float* pl = kb + (size_t)(c + 1) * HW;
#pragma unroll
            for (int s = 0; s < 4; s++) rg[s] = pl[gofs[s]];
            qn = qb[(size_t)(c + 1) * HW + p];
        }
        __syncthreads();  // sm ready
#pragma unroll
        for (int ki = 0; ki < 7; ki++) {
            const float* kib = smb + ki * 256;
#pragma unroll
            for (int kj = 0; kj < 7; kj++)
                sc[ki * 7 + kj] = fmaf(qc, kib[kj * 2], sc[ki * 7 + kj]);
        }
    }

    // prefetch v c=0 before softmax (overlaps softmax VALU)
#pragma unroll
    for (int s = 0; s < 4; s++) rg[s] = vb[gofs[s]];

    // ---- softmax over 49 ----
    float mx = sc[0];
#pragma unroll
    for (int u = 1; u < 49; u++) mx = fmaxf(mx, sc[u]);
    float sum = 0.0f;
#pragma unroll
    for (int u = 0; u < 49; u++) {
        sc[u] = __expf(sc[u] - mx);
        sum += sc[u];
    }
    float inv = 1.0f / sum;
#pragma unroll
    for (int u = 0; u < 49; u++) sc[u] *= inv;

    // ---- PV + LePE pass ----
    float* ob = out + ((size_t)b * 768 + n * 32) * HW + p;
    const float* wbase = wl + (size_t)(n * 32) * 25;
    const float* blb = bl + n * 32;
    for (int c = 0; c < 32; c++) {
        __syncthreads();
#pragma unroll
        for (int s = 0; s < 4; s++) sm[(ty + 4 * s) * WID + j] = rg[s];
        if (c < 31) {
            const float* pl = vb + (size_t)(c + 1) * HW;
#pragma unroll
            for (int s = 0; s < 4; s++) rg[s] = pl[gofs[s]];
        }
        __syncthreads();
        float oc = 0.0f;
#pragma unroll
        for (int ki = 0; ki < 7; ki++) {
            const float* kib = smb + ki * 256;
#pragma unroll
            for (int kj = 0; kj < 7; kj++)
                oc = fmaf(sc[ki * 7 + kj], kib[kj * 2], oc);
        }
        // LePE 5x5 depthwise from the same staged plane
        const float* wrow = wbase + c * 25;
        float lac = blb[c];
#pragma unroll
        for (int di = 0; di < 5; di++) {
            int ii = i + di - 2;
            if ((unsigned)ii < 128u) {
                const float* srow = sm + (ii - r0) * WID;
                const float* wr = wrow + di * 5;
#pragma unroll
                for (int dj = 0; dj < 5; dj++) {
                    int jj = j + dj - 2;
                    if ((unsigned)jj < 128u)
                        lac = fmaf(wr[dj], srow[jj], lac);
                }
            }
        }
        ob[(size_t)c * HW] = oc + lac;
    }
}

extern "C" void kernel_launch(void* const* d_in, const int* in_sizes, int n_in,
                              void* d_out, int out_size, void* d_ws, size_t ws_size,
                              hipStream_t stream) {
    const float* x = (const float*)d_in[0];
    const float* sinp = (const float*)d_in[1];
    const float* cosp = (const float*)d_in[2];
    const float* w_qkv = (const float*)d_in[3];
    const float* b_qkv = (const float*)d_in[4];
    const float* w_lepe = (const float*)d_in[5];
    const float* b_lepe = (const float*)d_in[6];
    const float* w_proj = (const float*)d_in[7];
    const float* b_proj = (const float*)d_in[8];
    const float* rpb = (const float*)d_in[9];
    float* out = (float*)d_out;

    // ws layout (256 MiB exactly):
    //   [0, 32 MiB)    xph: bf16-hi packed transposed operand [b][8][HW][32]
    //   [32, 64 MiB)   xpl: bf16-lo
    //   [64, 256 MiB)  qkvb: fp32 [b][768][HW]; q-region doubles as attn+lepe output
    unsigned short* xph = (unsigned short*)d_ws;
    unsigned short* xpl = xph + 16777216ull;
    float* qkvb = (float*)(xph + 33554432ull);

    // 1) split/transpose x
    pack_t<<<dim3(64, 8, 4), 256, 0, stream>>>(x, (size_t)256 * HW, xph, xpl);
    // 2) QKV projection (MFMA) + fused bias/RoPE/scale -> qkvb
    gemm_mfma<true><<<dim3(3072), 256, 0, stream>>>(w_qkv, xph, xpl, b_qkv, sinp, cosp,
                                                    qkvb, 6, 768);
    // 3) neighborhood attention + fused LePE -> q-region of qkvb
    attn_k<<<dim3(1024), 512, 0, stream>>>(qkvb, rpb, w_lepe, b_lepe, qkvb);
    // 4) split/transpose attn+lepe output
    pack_t<<<dim3(64, 8, 4), 256, 0, stream>>>(qkvb, (size_t)768 * HW, xph, xpl);
    // 5) output projection (MFMA) -> d_out
    gemm_mfma<false><<<dim3(1024), 256, 0, stream>>>(w_proj, xph, xpl, b_proj, nullptr, nullptr,
                                                     out, 2, 256);
}

// Round 8
// 464.823 us; speedup vs baseline: 1.1233x; 1.1233x over previous
//
#include <hip/hip_runtime.h>
#include <cstddef>

#define HW 16384
#define WID 128

typedef __attribute__((ext_vector_type(8))) short short8;
typedef __attribute__((ext_vector_type(4))) float f32x4;

__device__ __forceinline__ int wstart(int i) {
    // K=7, DIL=2, L=128: nh*d = 6
    if (i < 6) return i & 1;
    if (i >= 122) return 114 + (i & 1);
    return i - 6;
}
__device__ __forceinline__ int pbstart(int i) {
    if (i < 6) return 6 - (i >> 1);
    if (i >= 122) return (127 - i) >> 1;
    return 3;
}

__device__ __forceinline__ unsigned short bf16rne(float f) {
    unsigned u = __builtin_bit_cast(unsigned, f);
    u += 0x7FFFu + ((u >> 16) & 1u);
    return (unsigned short)(u >> 16);
}
__device__ __forceinline__ void bsplit(float f, unsigned short& h, unsigned short& l) {
    h = bf16rne(f);
    float hf = __builtin_bit_cast(float, ((unsigned)h) << 16);
    l = bf16rne(f - hf);
}

// ---------------- transpose + bf16 hi/lo split: [C][HW] fp32 -> [C/32][HW][32] ----------------
__global__ __launch_bounds__(256) void pack_t(const float* __restrict__ src, size_t bstr,
                                              unsigned short* __restrict__ dh,
                                              unsigned short* __restrict__ dl) {
    __shared__ float sm[32][260];
    const int p0 = blockIdx.x * 256, c32 = blockIdx.y, b = blockIdx.z;
    const float* s = src + (size_t)b * bstr + (size_t)(c32 * 32) * HW + p0;
    const int t = threadIdx.x;
    const int rr = t >> 3, f = t & 7;
#pragma unroll
    for (int u = 0; u < 8; u++) {
        float4 v = *(const float4*)(s + (size_t)rr * HW + (f + 8 * u) * 4);
        *(float4*)&sm[rr][(f + 8 * u) * 4] = v;
    }
    __syncthreads();
    size_t off = ((size_t)(b * 8 + c32) * HW + p0 + t) * 32;
#pragma unroll
    for (int w = 0; w < 4; w++) {
        short8 vh, vl;
#pragma unroll
        for (int e = 0; e < 8; e++) {
            unsigned short h, lo_;
            bsplit(sm[w * 8 + e][t], h, lo_);
            vh[e] = (short)h;
            vl[e] = (short)lo_;
        }
        *(short8*)&dh[off + w * 8] = vh;
        *(short8*)&dl[off + w * 8] = vl;
    }
}

// ---------------- split-bf16 MFMA GEMM (unchanged from round 6) ----------------
template <bool QKV>
__global__ __launch_bounds__(256, 2) void gemm_mfma(
    const float* __restrict__ Wm, const unsigned short* __restrict__ xh,
    const unsigned short* __restrict__ xl, const float* __restrict__ bias,
    const float* __restrict__ sinp, const float* __restrict__ cosp,
    float* __restrict__ Y, int NMT, int MT) {
    __shared__ unsigned short As_h[128][40], As_l[128][40];
    __shared__ unsigned short Bs_h[128][40], Bs_l[128][40];
    const int bid = blockIdx.x;
    const int xcd = bid & 7, r = bid >> 3;
    const int mt = r % NMT;
    const int q2 = r / NMT;
    const int nt = xcd * 16 + (q2 & 15);
    const int b = q2 >> 4;
    const int t = threadIdx.x;
    const int lane = t & 63, wid = t >> 6;
    const int wm = wid >> 1, wn = wid & 1;
    const int m0 = mt * 128;

    f32x4 acc[4][4];
#pragma unroll
    for (int i = 0; i < 4; i++)
#pragma unroll
        for (int j = 0; j < 4; j++) acc[i][j] = (f32x4){0.f, 0.f, 0.f, 0.f};

    const int sr = t >> 1, sh = t & 1;
    const float* arow = Wm + (size_t)(m0 + sr) * 256 + sh * 16;
    const unsigned short* bh_b = xh + ((size_t)(b * 8) * HW + (size_t)nt * 128 + sr) * 32 + sh * 16;
    const unsigned short* bl_b = xl + ((size_t)(b * 8) * HW + (size_t)nt * 128 + sr) * 32 + sh * 16;

    for (int ks = 0; ks < 8; ks++) {
        {
            const float* ap = arow + ks * 32;
#pragma unroll
            for (int g = 0; g < 2; g++) {
                float4 f0 = *(const float4*)(ap + g * 8);
                float4 f1 = *(const float4*)(ap + g * 8 + 4);
                float ff[8] = {f0.x, f0.y, f0.z, f0.w, f1.x, f1.y, f1.z, f1.w};
                short8 vh, vl;
#pragma unroll
                for (int e = 0; e < 8; e++) {
                    unsigned short h, lo_;
                    bsplit(ff[e], h, lo_);
                    vh[e] = (short)h;
                    vl[e] = (short)lo_;
                }
                *(short8*)&As_h[sr][sh * 16 + g * 8] = vh;
                *(short8*)&As_l[sr][sh * 16 + g * 8] = vl;
            }
        }
        {
            const unsigned short* bp = bh_b + (size_t)ks * HW * 32;
            const unsigned short* lp = bl_b + (size_t)ks * HW * 32;
            *(short8*)&Bs_h[sr][sh * 16] = *(const short8*)(bp);
            *(short8*)&Bs_h[sr][sh * 16 + 8] = *(const short8*)(bp + 8);
            *(short8*)&Bs_l[sr][sh * 16] = *(const short8*)(lp);
            *(short8*)&Bs_l[sr][sh * 16 + 8] = *(const short8*)(lp + 8);
        }
        __syncthreads();
        const int k8 = (lane >> 4) * 8;
        short8 a_h[4], a_l[4];
#pragma unroll
        for (int mi = 0; mi < 4; mi++) {
            int am = wm * 64 + mi * 16 + (lane & 15);
            a_h[mi] = *(const short8*)&As_h[am][k8];
            a_l[mi] = *(const short8*)&As_l[am][k8];
        }
#pragma unroll
        for (int ni = 0; ni < 4; ni++) {
            int bn = wn * 64 + ni * 16 + (lane & 15);
            short8 b_h = *(const short8*)&Bs_h[bn][k8];
            short8 b_l = *(const short8*)&Bs_l[bn][k8];
#pragma unroll
            for (int mi = 0; mi < 4; mi++) {
                acc[mi][ni] = __builtin_amdgcn_mfma_f32_16x16x32_bf16(a_h[mi], b_h, acc[mi][ni], 0, 0, 0);
                acc[mi][ni] = __builtin_amdgcn_mfma_f32_16x16x32_bf16(a_h[mi], b_l, acc[mi][ni], 0, 0, 0);
                acc[mi][ni] = __builtin_amdgcn_mfma_f32_16x16x32_bf16(a_l[mi], b_h, acc[mi][ni], 0, 0, 0);
            }
        }
        __syncthreads();
    }

    const int col = lane & 15, rq = (lane >> 4) * 4;
    const int s = QKV ? (mt >> 1) : 3;
#pragma unroll
    for (int mi = 0; mi < 4; mi++) {
        int mrow = m0 + wm * 64 + mi * 16 + rq;
        float b0 = bias[mrow], b1 = bias[mrow + 1], b2 = bias[mrow + 2], b3 = bias[mrow + 3];
#pragma unroll
        for (int ni = 0; ni < 4; ni++) {
            int p = nt * 128 + wn * 64 + ni * 16 + col;
            float v0 = acc[mi][ni][0] + b0, v1 = acc[mi][ni][1] + b1;
            float v2 = acc[mi][ni][2] + b2, v3 = acc[mi][ni][3] + b3;
            if (QKV && s < 2) {
                int d0 = (mi & 1) * 16 + rq;
                const float* cp = cosp + (size_t)p * 32 + d0;
                const float* sp = sinp + (size_t)p * 32 + d0;
                float c0 = cp[0], c1 = cp[1], c2 = cp[2], c3 = cp[3];
                float s0 = sp[0], s1 = sp[1], s2 = sp[2], s3 = sp[3];
                float n0 = v0 * c0 - v1 * s0, n1 = v1 * c1 + v0 * s1;
                float n2 = v2 * c2 - v3 * s2, n3 = v3 * c3 + v2 * s3;
                if (s == 0) {
                    const float sc = 0.17677669529663687f;
                    n0 *= sc; n1 *= sc; n2 *= sc; n3 *= sc;
                }
                v0 = n0; v1 = n1; v2 = n2; v3 = n3;
            }
            float* yp = Y + ((size_t)b * MT + mrow) * HW + p;
            yp[0] = v0;
            yp[HW] = v1;
            yp[2 * HW] = v2;
            yp[3 * HW] = v3;
        }
    }
}

// ---------------- Neighborhood attention + fused LePE, v3 ----------------
// 256 threads = 4 rows x 64 cols. Window 16 rows x 88 cols, 2 channels per
// stage, double-buffered LDS (2 x 11 KB), T14 async-stage (global->reg at
// iter top, ds_write at iter bottom, ONE barrier per 2 channels).
// XCD swizzle: 4 adjacent i-tiles per XCD for halo L2 reuse.
#define SW 88
#define CB 1408   // 16*88 floats, one channel window
#define BUF 2816  // 2 channels
__global__ __launch_bounds__(256) void attn_k(const float* __restrict__ qkv,
                                              const float* __restrict__ rpb,
                                              const float* __restrict__ wl,
                                              const float* __restrict__ bl,
                                              float* __restrict__ out) {
    __shared__ float sm[2 * BUF];
    const int t = threadIdx.x;
    const int ty = t >> 6;       // 0..3 (row within tile)
    const int lj = t & 63;       // col within tile
    const int bid = blockIdx.x;
    const int xcd = bid & 7, rr = bid >> 3;
    const int itc = rr & 3;
    const int jt = (rr >> 2) & 1;
    const int nb = rr >> 3;          // 0..31
    const int n = nb & 7, b = nb >> 3;
    const int it = xcd * 4 + itc;
    const int i0 = it * 4;
    const int j0 = jt * 64;
    const int i = i0 + ty;
    const int gj = j0 + lj;
    const int r0 = wstart(i0);       // window rows r0..r0+15
    const int wc0 = wstart(j0);      // window cols wc0..wc0+87

    const float* qb = qkv + ((size_t)b * 768 + n * 32) * HW;
    const float* kb = qb + (size_t)256 * HW;
    const float* vb = qb + (size_t)512 * HW;
    const int p = i * WID + gj;

    const int hs = wstart(i), ws_ = wstart(gj);
    const int ph = pbstart(i), pw = pbstart(gj);

    // staging offsets: linear d = u*256 + t over 2*CB floats; sel = channel
    int goff[11];
#pragma unroll
    for (int u = 0; u < 11; u++) {
        int d = u * 256 + t;
        int sel = d >= CB;
        int ld = d - sel * CB;
        int r = ld / SW;
        int cc = ld - r * SW;
        int grow = r0 + r; if (grow > 127) grow = 127;
        int gcol = wc0 + cc; if (gcol > 127) gcol = 127;
        goff[u] = sel * HW + grow * WID + gcol;
    }

    float sc[49];
    const float* rp = rpb + n * 169;
#pragma unroll
    for (int ki = 0; ki < 7; ki++)
#pragma unroll
        for (int kj = 0; kj < 7; kj++)
            sc[ki * 7 + kj] = rp[(ph + ki) * 13 + (pw + kj)];

    const int abase = (hs - r0) * SW + (ws_ - wc0);  // attn read base (dwords)
    const int lrow0 = i - 2 - r0;                    // lepe row base (local)
    const int lcol0 = gj - 2 - wc0;                  // lepe col base (local)

    float rg[11];
    // ---- prologue: stage k pair 0 into buf0 ----
#pragma unroll
    for (int u = 0; u < 11; u++) rg[u] = kb[goff[u]];
    float qnA = qb[p], qnB = qb[HW + p];
#pragma unroll
    for (int u = 0; u < 11; u++) sm[u * 256 + t] = rg[u];
    __syncthreads();

    // ---- QK^T: 16 c-pair iterations ----
    for (int cp = 0; cp < 16; cp++) {
        const int cur = cp & 1;
        // issue loads for next pair (or v pair 0 on last iter)
        const float* npl = (cp < 15) ? kb + (size_t)(cp + 1) * 2 * HW : vb;
#pragma unroll
        for (int u = 0; u < 11; u++) rg[u] = npl[goff[u]];
        float qA = qnA, qB = qnB;
        if (cp < 15) {
            qnA = qb[(size_t)(2 * cp + 2) * HW + p];
            qnB = qb[(size_t)(2 * cp + 3) * HW + p];
        }
        const float* s0 = sm + cur * BUF + abase;
        const float* s1 = s0 + CB;
#pragma unroll
        for (int ki = 0; ki < 7; ki++) {
            const float* a0 = s0 + ki * (2 * SW);
            const float* a1 = s1 + ki * (2 * SW);
#pragma unroll
            for (int kj = 0; kj < 7; kj++) {
                sc[ki * 7 + kj] = fmaf(qA, a0[kj * 2], sc[ki * 7 + kj]);
                sc[ki * 7 + kj] = fmaf(qB, a1[kj * 2], sc[ki * 7 + kj]);
            }
        }
        // write next pair into the other buffer
        float* dst = sm + (cur ^ 1) * BUF;
#pragma unroll
        for (int u = 0; u < 11; u++) dst[u * 256 + t] = rg[u];
        __syncthreads();
    }

    // ---- softmax over 49 (v pair 0 already staged in buf0) ----
    float mx = sc[0];
#pragma unroll
    for (int u = 1; u < 49; u++) mx = fmaxf(mx, sc[u]);
    float sum = 0.0f;
#pragma unroll
    for (int u = 0; u < 49; u++) {
        sc[u] = __expf(sc[u] - mx);
        sum += sc[u];
    }
    float inv = 1.0f / sum;
#pragma unroll
    for (int u = 0; u < 49; u++) sc[u] *= inv;

    // ---- PV + LePE: 16 c-pair iterations ----
    float* ob = out + ((size_t)b * 768 + n * 32) * HW + p;
    const float* wbase = wl + (size_t)(n * 32) * 25;
    const float* blb = bl + n * 32;
    for (int cp = 0; cp < 16; cp++) {
        const int cur = cp & 1;
        if (cp < 15) {
            const float* npl = vb + (size_t)(cp + 1) * 2 * HW;
#pragma unroll
            for (int u = 0; u < 11; u++) rg[u] = npl[goff[u]];
        }
#pragma unroll
        for (int ch = 0; ch < 2; ch++) {
            const int cc = 2 * cp + ch;
            const float* sv = sm + cur * BUF + ch * CB;
            const float* sa = sv + abase;
            float oc = 0.0f;
#pragma unroll
            for (int ki = 0; ki < 7; ki++) {
                const float* a0 = sa + ki * (2 * SW);
#pragma unroll
                for (int kj = 0; kj < 7; kj++)
                    oc = fmaf(sc[ki * 7 + kj], a0[kj * 2], oc);
            }
            // LePE 5x5 from same staged plane
            const float* wrow = wbase + cc * 25;
            float lac = blb[cc];
#pragma unroll
            for (int di = 0; di < 5; di++) {
                int ii = i + di - 2;
                if ((unsigned)ii < 128u) {
                    const float* srow = sv + (lrow0 + di) * SW + lcol0;
                    const float* wr = wrow + di * 5;
#pragma unroll
                    for (int dj = 0; dj < 5; dj++) {
                        int jj = gj + dj - 2;
                        if ((unsigned)jj < 128u)
                            lac = fmaf(wr[dj], srow[dj], lac);
                    }
                }
            }
            ob[(size_t)cc * HW] = oc + lac;
        }
        if (cp < 15) {
            float* dst = sm + (cur ^ 1) * BUF;
#pragma unroll
            for (int u = 0; u < 11; u++) dst[u * 256 + t] = rg[u];
        }
        __syncthreads();
    }
}

extern "C" void kernel_launch(void* const* d_in, const int* in_sizes, int n_in,
                              void* d_out, int out_size, void* d_ws, size_t ws_size,
                              hipStream_t stream) {
    const float* x = (const float*)d_in[0];
    const float* sinp = (const float*)d_in[1];
    const float* cosp = (const float*)d_in[2];
    const float* w_qkv = (const float*)d_in[3];
    const float* b_qkv = (const float*)d_in[4];
    const float* w_lepe = (const float*)d_in[5];
    const float* b_lepe = (const float*)d_in[6];
    const float* w_proj = (const float*)d_in[7];
    const float* b_proj = (const float*)d_in[8];
    const float* rpb = (const float*)d_in[9];
    float* out = (float*)d_out;

    unsigned short* xph = (unsigned short*)d_ws;
    unsigned short* xpl = xph + 16777216ull;
    float* qkvb = (float*)(xph + 33554432ull);

    // 1) split/transpose x
    pack_t<<<dim3(64, 8, 4), 256, 0, stream>>>(x, (size_t)256 * HW, xph, xpl);
    // 2) QKV projection (MFMA) + fused bias/RoPE/scale -> qkvb
    gemm_mfma<true><<<dim3(3072), 256, 0, stream>>>(w_qkv, xph, xpl, b_qkv, sinp, cosp,
                                                    qkvb, 6, 768);
    // 3) neighborhood attention + fused LePE -> q-region of qkvb
    attn_k<<<dim3(2048), 256, 0, stream>>>(qkvb, rpb, w_lepe, b_lepe, qkvb);
    // 4) split/transpose attn+lepe output
    pack_t<<<dim3(64, 8, 4), 256, 0, stream>>>(qkvb, (size_t)768 * HW, xph, xpl);
    // 5) output projection (MFMA) -> d_out
    gemm_mfma<false><<<dim3(1024), 256, 0, stream>>>(w_proj, xph, xpl, b_proj, nullptr, nullptr,
                                                     out, 2, 256);
}

// Round 9
// 421.324 us; speedup vs baseline: 1.2392x; 1.1032x over previous
//
#include <hip/hip_runtime.h>
#include <cstddef>

#define HW 16384
#define WID 128

typedef __attribute__((ext_vector_type(8))) short short8;
typedef __attribute__((ext_vector_type(4))) float f32x4;

// async global->LDS, 4B per lane; LDS dest = wave-uniform base + lane*4
#define GLD4(g, l)                                                        \
    __builtin_amdgcn_global_load_lds(                                     \
        (const __attribute__((address_space(1))) unsigned int*)(g),       \
        (__attribute__((address_space(3))) unsigned int*)(l), 4, 0, 0)

__device__ __forceinline__ int wstart(int i) {
    // K=7, DIL=2, L=128: nh*d = 6
    if (i < 6) return i & 1;
    if (i >= 122) return 114 + (i & 1);
    return i - 6;
}
__device__ __forceinline__ int pbstart(int i) {
    if (i < 6) return 6 - (i >> 1);
    if (i >= 122) return (127 - i) >> 1;
    return 3;
}

__device__ __forceinline__ unsigned short bf16rne(float f) {
    unsigned u = __builtin_bit_cast(unsigned, f);
    u += 0x7FFFu + ((u >> 16) & 1u);
    return (unsigned short)(u >> 16);
}
__device__ __forceinline__ void bsplit(float f, unsigned short& h, unsigned short& l) {
    h = bf16rne(f);
    float hf = __builtin_bit_cast(float, ((unsigned)h) << 16);
    l = bf16rne(f - hf);
}

// ---------------- transpose + bf16 hi/lo split: [C][HW] fp32 -> [C/32][HW][32] ----------------
__global__ __launch_bounds__(256) void pack_t(const float* __restrict__ src, size_t bstr,
                                              unsigned short* __restrict__ dh,
                                              unsigned short* __restrict__ dl) {
    __shared__ float sm[32][260];
    const int p0 = blockIdx.x * 256, c32 = blockIdx.y, b = blockIdx.z;
    const float* s = src + (size_t)b * bstr + (size_t)(c32 * 32) * HW + p0;
    const int t = threadIdx.x;
    const int rr = t >> 3, f = t & 7;
#pragma unroll
    for (int u = 0; u < 8; u++) {
        float4 v = *(const float4*)(s + (size_t)rr * HW + (f + 8 * u) * 4);
        *(float4*)&sm[rr][(f + 8 * u) * 4] = v;
    }
    __syncthreads();
    size_t off = ((size_t)(b * 8 + c32) * HW + p0 + t) * 32;
#pragma unroll
    for (int w = 0; w < 4; w++) {
        short8 vh, vl;
#pragma unroll
        for (int e = 0; e < 8; e++) {
            unsigned short h, lo_;
            bsplit(sm[w * 8 + e][t], h, lo_);
            vh[e] = (short)h;
            vl[e] = (short)lo_;
        }
        *(short8*)&dh[off + w * 8] = vh;
        *(short8*)&dl[off + w * 8] = vl;
    }
}

// ---------------- split-bf16 MFMA GEMM (unchanged from round 6) ----------------
template <bool QKV>
__global__ __launch_bounds__(256, 2) void gemm_mfma(
    const float* __restrict__ Wm, const unsigned short* __restrict__ xh,
    const unsigned short* __restrict__ xl, const float* __restrict__ bias,
    const float* __restrict__ sinp, const float* __restrict__ cosp,
    float* __restrict__ Y, int NMT, int MT) {
    __shared__ unsigned short As_h[128][40], As_l[128][40];
    __shared__ unsigned short Bs_h[128][40], Bs_l[128][40];
    const int bid = blockIdx.x;
    const int xcd = bid & 7, r = bid >> 3;
    const int mt = r % NMT;
    const int q2 = r / NMT;
    const int nt = xcd * 16 + (q2 & 15);
    const int b = q2 >> 4;
    const int t = threadIdx.x;
    const int lane = t & 63, wid = t >> 6;
    const int wm = wid >> 1, wn = wid & 1;
    const int m0 = mt * 128;

    f32x4 acc[4][4];
#pragma unroll
    for (int i = 0; i < 4; i++)
#pragma unroll
        for (int j = 0; j < 4; j++) acc[i][j] = (f32x4){0.f, 0.f, 0.f, 0.f};

    const int sr = t >> 1, sh = t & 1;
    const float* arow = Wm + (size_t)(m0 + sr) * 256 + sh * 16;
    const unsigned short* bh_b = xh + ((size_t)(b * 8) * HW + (size_t)nt * 128 + sr) * 32 + sh * 16;
    const unsigned short* bl_b = xl + ((size_t)(b * 8) * HW + (size_t)nt * 128 + sr) * 32 + sh * 16;

    for (int ks = 0; ks < 8; ks++) {
        {
            const float* ap = arow + ks * 32;
#pragma unroll
            for (int g = 0; g < 2; g++) {
                float4 f0 = *(const float4*)(ap + g * 8);
                float4 f1 = *(const float4*)(ap + g * 8 + 4);
                float ff[8] = {f0.x, f0.y, f0.z, f0.w, f1.x, f1.y, f1.z, f1.w};
                short8 vh, vl;
#pragma unroll
                for (int e = 0; e < 8; e++) {
                    unsigned short h, lo_;
                    bsplit(ff[e], h, lo_);
                    vh[e] = (short)h;
                    vl[e] = (short)lo_;
                }
                *(short8*)&As_h[sr][sh * 16 + g * 8] = vh;
                *(short8*)&As_l[sr][sh * 16 + g * 8] = vl;
            }
        }
        {
            const unsigned short* bp = bh_b + (size_t)ks * HW * 32;
            const unsigned short* lp = bl_b + (size_t)ks * HW * 32;
            *(short8*)&Bs_h[sr][sh * 16] = *(const short8*)(bp);
            *(short8*)&Bs_h[sr][sh * 16 + 8] = *(const short8*)(bp + 8);
            *(short8*)&Bs_l[sr][sh * 16] = *(const short8*)(lp);
            *(short8*)&Bs_l[sr][sh * 16 + 8] = *(const short8*)(lp + 8);
        }
        __syncthreads();
        const int k8 = (lane >> 4) * 8;
        short8 a_h[4], a_l[4];
#pragma unroll
        for (int mi = 0; mi < 4; mi++) {
            int am = wm * 64 + mi * 16 + (lane & 15);
            a_h[mi] = *(const short8*)&As_h[am][k8];
            a_l[mi] = *(const short8*)&As_l[am][k8];
        }
#pragma unroll
        for (int ni = 0; ni < 4; ni++) {
            int bn = wn * 64 + ni * 16 + (lane & 15);
            short8 b_h = *(const short8*)&Bs_h[bn][k8];
            short8 b_l = *(const short8*)&Bs_l[bn][k8];
#pragma unroll
            for (int mi = 0; mi < 4; mi++) {
                acc[mi][ni] = __builtin_amdgcn_mfma_f32_16x16x32_bf16(a_h[mi], b_h, acc[mi][ni], 0, 0, 0);
                acc[mi][ni] = __builtin_amdgcn_mfma_f32_16x16x32_bf16(a_h[mi], b_l, acc[mi][ni], 0, 0, 0);
                acc[mi][ni] = __builtin_amdgcn_mfma_f32_16x16x32_bf16(a_l[mi], b_h, acc[mi][ni], 0, 0, 0);
            }
        }
        __syncthreads();
    }

    const int col = lane & 15, rq = (lane >> 4) * 4;
    const int s = QKV ? (mt >> 1) : 3;
#pragma unroll
    for (int mi = 0; mi < 4; mi++) {
        int mrow = m0 + wm * 64 + mi * 16 + rq;
        float b0 = bias[mrow], b1 = bias[mrow + 1], b2 = bias[mrow + 2], b3 = bias[mrow + 3];
#pragma unroll
        for (int ni = 0; ni < 4; ni++) {
            int p = nt * 128 + wn * 64 + ni * 16 + col;
            float v0 = acc[mi][ni][0] + b0, v1 = acc[mi][ni][1] + b1;
            float v2 = acc[mi][ni][2] + b2, v3 = acc[mi][ni][3] + b3;
            if (QKV && s < 2) {
                int d0 = (mi & 1) * 16 + rq;
                const float* cp = cosp + (size_t)p * 32 + d0;
                const float* sp = sinp + (size_t)p * 32 + d0;
                float c0 = cp[0], c1 = cp[1], c2 = cp[2], c3 = cp[3];
                float s0 = sp[0], s1 = sp[1], s2 = sp[2], s3 = sp[3];
                float n0 = v0 * c0 - v1 * s0, n1 = v1 * c1 + v0 * s1;
                float n2 = v2 * c2 - v3 * s2, n3 = v3 * c3 + v2 * s3;
                if (s == 0) {
                    const float sc = 0.17677669529663687f;
                    n0 *= sc; n1 *= sc; n2 *= sc; n3 *= sc;
                }
                v0 = n0; v1 = n1; v2 = n2; v3 = n3;
            }
            float* yp = Y + ((size_t)b * MT + mrow) * HW + p;
            yp[0] = v0;
            yp[HW] = v1;
            yp[2 * HW] = v2;
            yp[3 * HW] = v3;
        }
    }
}

// ---------------- Neighborhood attention + fused LePE, v4 ----------------
// Round-6 geometry (256 thr = 2 rows x 128 cols, 14x128 window) but staged via
// global_load_lds DMA into a double buffer with counted vmcnt (T3/T4 2-phase):
// channel c+1's 8 DMAs (7 window rows + 1 q row) are in flight during channel
// c's compute; s_waitcnt vmcnt(8) + raw s_barrier, never vmcnt(0) mid-loop.
// No register staging -> VGPR stays low -> 8 blocks/CU residency.
#define CBUF 2048  // 14*128 window + 256 q-row slots
__global__ __launch_bounds__(256) void attn_k(const float* __restrict__ qkv,
                                              const float* __restrict__ rpb,
                                              const float* __restrict__ wl,
                                              const float* __restrict__ bl,
                                              float* __restrict__ out) {
    __shared__ float sm[2 * CBUF];
    const int t = threadIdx.x;
    const int ty = t >> 7;
    const int j = t & 127;
    const int i0 = blockIdx.x * 2;
    const int i = i0 + ty;
    const int n = blockIdx.y, b = blockIdx.z;
    const int r0 = wstart(i0);
    const int w64 = (t >> 6) * 64;  // wave-uniform LDS base offset

    const float* qb = qkv + ((size_t)b * 768 + n * 32) * HW;
    const float* kb = qb + (size_t)256 * HW;
    const float* vb = qb + (size_t)512 * HW;
    const int p = i * WID + j;
    const float* qrow = qb + i0 * WID;  // + c*HW + t
    const float* krow = kb + r0 * WID;
    const float* vrow = vb + r0 * WID;

    const int hs = wstart(i), ws_ = wstart(j);
    const int ph = pbstart(i), pw = pbstart(j);

    float sc[49];
    const float* rp = rpb + n * 169;
#pragma unroll
    for (int ki = 0; ki < 7; ki++)
#pragma unroll
        for (int kj = 0; kj < 7; kj++)
            sc[ki * 7 + kj] = rp[(ph + ki) * 13 + (pw + kj)];

    const int aoff = (hs - r0) * WID + ws_;  // attn tap base within window

    // prologue: issue channel-0 k window + q into buf0
#pragma unroll
    for (int u = 0; u < 7; u++) GLD4(krow + u * 256 + t, &sm[u * 256 + w64]);
    GLD4(qrow + t, &sm[1792 + w64]);

    // ---- QK^T: per channel, issue c+1 then wait for c (vmcnt(8)) ----
    for (int c = 0; c < 32; c++) {
        float* bc = sm + (c & 1) * CBUF;
        float* bnx = sm + ((c + 1) & 1) * CBUF;
        if (c < 31) {
            const float* kp = krow + (size_t)(c + 1) * HW;
#pragma unroll
            for (int u = 0; u < 7; u++) GLD4(kp + u * 256 + t, &bnx[u * 256 + w64]);
            GLD4(qrow + (size_t)(c + 1) * HW + t, &bnx[1792 + w64]);
            asm volatile("s_waitcnt vmcnt(8)" ::: "memory");
        } else {
            // issue v channel 0 (7 rows, no q) so it flies during softmax
#pragma unroll
            for (int u = 0; u < 7; u++) GLD4(vrow + u * 256 + t, &bnx[u * 256 + w64]);
            asm volatile("s_waitcnt vmcnt(7)" ::: "memory");
        }
        __builtin_amdgcn_s_barrier();
        float qc = bc[1792 + t];
        const float* smb = bc + aoff;
#pragma unroll
        for (int ki = 0; ki < 7; ki++) {
            const float* kib = smb + ki * 256;
#pragma unroll
            for (int kj = 0; kj < 7; kj++)
                sc[ki * 7 + kj] = fmaf(qc, kib[kj * 2], sc[ki * 7 + kj]);
        }
        __builtin_amdgcn_s_barrier();  // readers of bc done -> bc reusable
    }

    // ---- softmax over 49 (v0 window in flight) ----
    float mx = sc[0];
#pragma unroll
    for (int u = 1; u < 49; u++) mx = fmaxf(mx, sc[u]);
    float sum = 0.0f;
#pragma unroll
    for (int u = 0; u < 49; u++) {
        sc[u] = __expf(sc[u] - mx);
        sum += sc[u];
    }
    float inv = 1.0f / sum;
#pragma unroll
    for (int u = 0; u < 49; u++) sc[u] *= inv;

    // ---- PV + LePE: same 2-phase pipeline over v channels ----
    float* ob = out + ((size_t)b * 768 + n * 32) * HW + p;
    const float* wbase = wl + (size_t)(n * 32) * 25;
    const float* blb = bl + n * 32;
    for (int c = 0; c < 32; c++) {
        float* bc = sm + (c & 1) * CBUF;
        float* bnx = sm + ((c + 1) & 1) * CBUF;
        if (c < 31) {
            const float* vp = vrow + (size_t)(c + 1) * HW;
#pragma unroll
            for (int u = 0; u < 7; u++) GLD4(vp + u * 256 + t, &bnx[u * 256 + w64]);
            asm volatile("s_waitcnt vmcnt(7)" ::: "memory");
        } else {
            asm volatile("s_waitcnt vmcnt(0)" ::: "memory");
        }
        __builtin_amdgcn_s_barrier();
        const float* smb = bc + aoff;
        float oc = 0.0f;
#pragma unroll
        for (int ki = 0; ki < 7; ki++) {
            const float* kib = smb + ki * 256;
#pragma unroll
            for (int kj = 0; kj < 7; kj++)
                oc = fmaf(sc[ki * 7 + kj], kib[kj * 2], oc);
        }
        // LePE 5x5 depthwise from the same staged window
        const float* wrow = wbase + c * 25;
        float lac = blb[c];
#pragma unroll
        for (int di = 0; di < 5; di++) {
            int ii = i + di - 2;
            if ((unsigned)ii < 128u) {
                const float* srow = bc + (ii - r0) * WID;
                const float* wr = wrow + di * 5;
#pragma unroll
                for (int dj = 0; dj < 5; dj++) {
                    int jj = j + dj - 2;
                    if ((unsigned)jj < 128u)
                        lac = fmaf(wr[dj], srow[jj], lac);
                }
            }
        }
        ob[(size_t)c * HW] = oc + lac;
        __builtin_amdgcn_s_barrier();  // readers of bc done -> bc reusable
    }
}

extern "C" void kernel_launch(void* const* d_in, const int* in_sizes, int n_in,
                              void* d_out, int out_size, void* d_ws, size_t ws_size,
                              hipStream_t stream) {
    const float* x = (const float*)d_in[0];
    const float* sinp = (const float*)d_in[1];
    const float* cosp = (const float*)d_in[2];
    const float* w_qkv = (const float*)d_in[3];
    const float* b_qkv = (const float*)d_in[4];
    const float* w_lepe = (const float*)d_in[5];
    const float* b_lepe = (const float*)d_in[6];
    const float* w_proj = (const float*)d_in[7];
    const float* b_proj = (const float*)d_in[8];
    const float* rpb = (const float*)d_in[9];
    float* out = (float*)d_out;

    unsigned short* xph = (unsigned short*)d_ws;
    unsigned short* xpl = xph + 16777216ull;
    float* qkvb = (float*)(xph + 33554432ull);

    // 1) split/transpose x
    pack_t<<<dim3(64, 8, 4), 256, 0, stream>>>(x, (size_t)256 * HW, xph, xpl);
    // 2) QKV projection (MFMA) + fused bias/RoPE/scale -> qkvb
    gemm_mfma<true><<<dim3(3072), 256, 0, stream>>>(w_qkv, xph, xpl, b_qkv, sinp, cosp,
                                                    qkvb, 6, 768);
    // 3) neighborhood attention + fused LePE -> q-region of qkvb
    attn_k<<<dim3(64, 8, 4), 256, 0, stream>>>(qkvb, rpb, w_lepe, b_lepe, qkvb);
    // 4) split/transpose attn+lepe output
    pack_t<<<dim3(64, 8, 4), 256, 0, stream>>>(qkvb, (size_t)768 * HW, xph, xpl);
    // 5) output projection (MFMA) -> d_out
    gemm_mfma<false><<<dim3(1024), 256, 0, stream>>>(w_proj, xph, xpl, b_proj, nullptr, nullptr,
                                                     out, 2, 256);
}